// Round 7
// baseline (194.494 us; speedup 1.0000x reference)
//
#include <hip/hip_runtime.h>

typedef _Float16 half8 __attribute__((ext_vector_type(8)));
typedef __fp16  fp16x2 __attribute__((ext_vector_type(2)));
typedef float f32x4 __attribute__((ext_vector_type(4)));

#define HH 6144
#define WW 6144
#define KH 11
#define KW 11
#define OH (HH - KH + 1)   // 6134
#define OW (WW - KW + 1)   // 6134

#define BROWS 64           // out rows per block (wave w owns rows 16w..16w+15)
#define BCOLS 128          // out cols per block (8 col-tiles of 16)
#define SROWS 74           // staged input rows  (16*3+15+10 = 73 max)
#define SCOLS 144          // staged input cols  (16*7+31 = 143 max)
#define RS 164             // LDS row stride in halves (328 B; 82 dw = 18 mod 32 -> ~2-way)

#define NTASK (SROWS * (SCOLS / 4))   // 2664 float4 stage tasks

#define TILES_X 48         // ceil(6134/128)
#define TILES_Y 96         // ceil(6134/64)
#define NWG (TILES_X * TILES_Y)       // 4608 (divisible by 8)

// ---- prep: B fragments in exact lane order -------------------------------
// Bp[(kb*64 + l)*8 + e] = B[k=kb*32 + (l>>4)*8 + e][n=l&15] = W[kb][q-n]
__global__ void build_B_kernel(const float* __restrict__ Wt,
                               _Float16* __restrict__ Bp) {
    const int t = (int)blockIdx.x * 256 + (int)threadIdx.x;
    if (t < 11 * 64 * 8) {
        const int e  = t & 7;
        const int l  = (t >> 3) & 63;
        const int kb = t >> 9;          // = ki
        const int n  = l & 15;
        const int q  = (l >> 4) * 8 + e;
        const int d  = q - n;
        float v = (d >= 0 && d < KW) ? Wt[kb * KW + d] : 0.f;
        Bp[t] = (_Float16)v;
    }
}

union pk2 { fp16x2 h; unsigned int u; };
static __device__ inline unsigned int cvt2(float a, float b) {
#if defined(__has_builtin) && __has_builtin(__builtin_amdgcn_cvt_pkrtz)
    pk2 r; r.h = __builtin_amdgcn_cvt_pkrtz(a, b);
#else
    pk2 r; r.h[0] = (__fp16)a; r.h[1] = (__fp16)b;
#endif
    return r.u;
}

__global__ __launch_bounds__(256, 3)
void conv2d_mfma2_kernel(const float* __restrict__ X,
                         const _Float16* __restrict__ Bp,
                         const float* __restrict__ bias,
                         float* __restrict__ out)
{
    __shared__ _Float16 lds[SROWS * RS];    // 24272 B, row-major

    // XCD-aware remap: each XCD owns 6 tile-columns, traversed column-major
    const int bid = (int)blockIdx.x;
    const int xcd = bid & 7;
    const int loc = bid >> 3;                   // 0..575
    const int txt = xcd * 6 + loc / TILES_Y;    // 0..47
    const int tyt = loc % TILES_Y;              // 0..95

    const int x0 = txt * BCOLS;
    const int y0 = tyt * BROWS;
    const int tid = (int)threadIdx.x;
    const int lane = tid & 63;
    const int n = lane & 15;
    const int h = lane >> 4;
    const int w = tid >> 6;

    // ---- B (weight) fragments: 11 coalesced 16B loads, L2-hot -------------
    const _Float16* bp = Bp + (size_t)lane * 8;
    half8 Bf[11];
    #pragma unroll
    for (int kb = 0; kb < 11; ++kb)
        Bf[kb] = *reinterpret_cast<const half8*>(bp + kb * 64 * 8);

    const float bv = bias[0];

    // ---- stage X tile: row-major fp16, float4 -> cvt_pkrtz x2 -> 8B write --
    const bool interiorS = (x0 + SCOLS <= WW) && (y0 + SROWS <= HH);
    if (interiorS) {
        #pragma unroll
        for (int it = 0; it < 11; ++it) {
            const int idx = it * 256 + tid;
            if (idx < NTASK) {
                const int row = idx / 36;
                const int j   = idx - row * 36;
                const float4 v = *reinterpret_cast<const float4*>(
                    &X[(size_t)(y0 + row) * WW + (x0 + 4 * j)]);
                uint2 pk;
                pk.x = cvt2(v.x, v.y);
                pk.y = cvt2(v.z, v.w);
                *reinterpret_cast<uint2*>(&lds[row * RS + 4 * j]) = pk;
            }
        }
    } else {
        #pragma unroll
        for (int it = 0; it < 11; ++it) {
            const int idx = it * 256 + tid;
            if (idx < NTASK) {
                const int row = idx / 36;
                const int j   = idx - row * 36;
                const int gy  = y0 + row;
                const int gx  = x0 + 4 * j;
                float v0 = 0.f, v1 = 0.f, v2 = 0.f, v3 = 0.f;
                if (gy < HH) {
                    const float* rp = X + (size_t)gy * WW;
                    if (gx + 0 < WW) v0 = rp[gx + 0];
                    if (gx + 1 < WW) v1 = rp[gx + 1];
                    if (gx + 2 < WW) v2 = rp[gx + 2];
                    if (gx + 3 < WW) v3 = rp[gx + 3];
                }
                uint2 pk;
                pk.x = cvt2(v0, v1);
                pk.y = cvt2(v2, v3);
                *reinterpret_cast<uint2*>(&lds[row * RS + 4 * j]) = pk;
            }
        }
    }

    f32x4 acc[8];
    #pragma unroll
    for (int t = 0; t < 8; ++t) acc[t] = (f32x4){bv, bv, bv, bv};

    __syncthreads();

    // ---- compute: A-frag = one b128 (base + const offset), zero inner VALU -
    // A(kb,t) lane(m=n,h): X row 16w+m+kb, cols 16t + 8h + [0,8)
    const char* ab = reinterpret_cast<const char*>(lds)
                   + ((16 * w + n) * RS + 8 * h) * 2;
    #pragma unroll
    for (int kb = 0; kb < 11; ++kb) {
        #pragma unroll
        for (int t = 0; t < 8; ++t) {
            half8 a = *reinterpret_cast<const half8*>(ab + kb * (RS * 2) + t * 32);
            acc[t] = __builtin_amdgcn_mfma_f32_16x16x32_f16(a, Bf[kb], acc[t], 0, 0, 0);
        }
    }

    // ---- store: D row = 4h + reg (out row 16w+4h+r), col = n (out col 16t+n)
    const int gy0 = y0 + 16 * w + 4 * h;
    const int gx0 = x0 + n;
    const bool interiorD = (x0 + BCOLS <= OW) && (y0 + BROWS <= OH);
    if (interiorD) {
        #pragma unroll
        for (int r = 0; r < 4; ++r) {
            float* op = out + (size_t)(gy0 + r) * OW + gx0;
            #pragma unroll
            for (int t = 0; t < 8; ++t)
                op[t * 16] = acc[t][r];
        }
    } else {
        #pragma unroll
        for (int r = 0; r < 4; ++r) {
            const int oy = gy0 + r;
            if (oy < OH) {
                float* op = out + (size_t)oy * OW + gx0;
                #pragma unroll
                for (int t = 0; t < 8; ++t)
                    if (gx0 + t * 16 < OW) op[t * 16] = acc[t][r];
            }
        }
    }
}

extern "C" void kernel_launch(void* const* d_in, const int* in_sizes, int n_in,
                              void* d_out, int out_size, void* d_ws, size_t ws_size,
                              hipStream_t stream) {
    const float* X    = (const float*)d_in[0];
    const float* Wt   = (const float*)d_in[1];
    const float* bias = (const float*)d_in[2];
    float* out        = (float*)d_out;
    _Float16* Bp      = (_Float16*)d_ws;      // 11*64*8*2 = 11264 B

    build_B_kernel<<<dim3(22), dim3(256), 0, stream>>>(Wt, Bp);
    conv2d_mfma2_kernel<<<dim3(NWG), dim3(256), 0, stream>>>(X, Bp, bias, out);
}